// Round 7
// baseline (668.346 us; speedup 1.0000x reference)
//
#include <hip/hip_runtime.h>

#define NTOT 262144   // B*L
#define NLAY 8
#define SEGOUT 48     // useful nodes per 64-lane wave (64 nodes incl. 8+8 halo)
#define NSEG ((NTOT + SEGOUT - 1) / SEGOUT)   // 5462

// silu via v_rcp_f32: harness compiles WITHOUT fast-math, so 1.0f/x emits the
// full IEEE divide expansion (~10 VALU ops). v_rcp is 1 op, ~1 ulp — noise vs
// the 2.4e-4 absmax budget. Same for v_sqrt.
__device__ __forceinline__ float silu_f(float x) {
    return x * __builtin_amdgcn_rcpf(1.0f + __expf(-x));
}

// ---------------- Kernel 1: encode  (mask/pos -> h0, pos0) ----------------
// R7 rewrite: node-per-thread, direct-global streaming. No LDS, no barriers,
// no shuffles, no 8x MLP replication. Adjacent lanes stride 148B, so every
// fetched cache line is fully consumed through L1/L2 -> still BW-dense.
// embW reads are wave-uniform -> scalar pipe (s_load), zero VGPR cost
// (R5 lesson: uniform weights must stay on the scalar path).
// R3 lesson respected: no guarded per-element LDS staging anywhere.
__global__ __launch_bounds__(256) void k_encode(
    const float* __restrict__ ap, const float* __restrict__ amask,
    const float* __restrict__ embW, const float* __restrict__ embB,
    const float* __restrict__ peW1, const float* __restrict__ peB1,
    const float* __restrict__ peW2, const float* __restrict__ peB2,
    float* __restrict__ h0, float* __restrict__ pos0)
{
    const long n = (long)blockIdx.x * 256 + threadIdx.x;   // grid covers NTOT exactly
    const float* mrow = amask + n * 37;
    const float* arow = ap + n * 111;

    float hacc[8] = {0, 0, 0, 0, 0, 0, 0, 0};
    float ps0 = 0.f, ps1 = 0.f, ps2 = 0.f, msum = 0.f;

    #pragma unroll 1
    for (int k = 0; k < 37; ++k) {
        float mv = mrow[k];
        msum += mv;
        const float* wr = embW + k * 8;      // uniform -> s_load
        #pragma unroll
        for (int j = 0; j < 8; ++j) hacc[j] += mv * wr[j];
        ps0 += mv * arow[k * 3 + 0];
        ps1 += mv * arow[k * 3 + 1];
        ps2 += mv * arow[k * 3 + 2];
    }

    float inv = __builtin_amdgcn_rcpf(msum + 1e-8f);
    float mp0 = ps0 * inv, mp1 = ps1 * inv, mp2 = ps2 * inv;

    float q[8];
    #pragma unroll
    for (int j = 0; j < 8; ++j) {
        float a = peB1[j];
        a += mp0 * peW1[0 * 8 + j];
        a += mp1 * peW1[1 * 8 + j];
        a += mp2 * peW1[2 * 8 + j];
        q[j] = silu_f(a);
    }
    #pragma unroll
    for (int j = 0; j < 8; ++j) {
        float a = peB2[j] + embB[j];
        #pragma unroll
        for (int r = 0; r < 8; ++r) a += q[r] * peW2[r * 8 + j];
        hacc[j] += a;
    }

    float4* hd = (float4*)(h0 + n * 8);
    hd[0] = make_float4(hacc[0], hacc[1], hacc[2], hacc[3]);
    hd[1] = make_float4(hacc[4], hacc[5], hacc[6], hacc[7]);
    ((float4*)pos0)[n] = make_float4(mp0, mp1, mp2, 0.f);
}

// ---------------- Kernel 2: fused 8-layer SE3 stack + mid latent ----------
// R2-proven version, verbatim. Wave-autonomous, 1 node/lane, 8+8 halo,
// __shfl neighbor exchange, NO LDS, NO barriers. Weights via global scalar
// path (s_load/SGPR) — do NOT stage in LDS (R5: VGPR 48->224, 10% occ).
__device__ __forceinline__ void edge_mlp(
    const float* __restrict__ wE1, const float* __restrict__ bE1,
    const float* __restrict__ wE2, const float* __restrict__ bE2,
    const float* __restrict__ wP1, const float* __restrict__ bP1,
    const float* __restrict__ wP2,
    const float* hl, const float* hr, float r0, float r1, float r2,
    float* ea, float& dp0, float& dp1, float& dp2)
{
    float dist = __builtin_amdgcn_sqrtf(r0 * r0 + r1 * r1 + r2 * r2);
    float t1[8];
    #pragma unroll
    for (int j = 0; j < 8; ++j) {
        float a = bE1[j];
        #pragma unroll
        for (int r = 0; r < 8; ++r) a += hl[r] * wE1[r * 8 + j];
        #pragma unroll
        for (int r = 0; r < 8; ++r) a += hr[r] * wE1[64 + r * 8 + j];
        a += dist * wE1[128 + j];
        t1[j] = silu_f(a);
    }
    #pragma unroll
    for (int j = 0; j < 8; ++j) {
        float a = bE2[j];
        #pragma unroll
        for (int r = 0; r < 8; ++r) a += t1[r] * wE2[r * 8 + j];
        ea[j] = a;
    }
    float q[8];
    #pragma unroll
    for (int j = 0; j < 8; ++j) {
        float a = bP1[j];
        #pragma unroll
        for (int r = 0; r < 8; ++r) a += ea[r] * wP1[r * 8 + j];
        q[j] = silu_f(a);
    }
    dp0 = 0.f; dp1 = 0.f; dp2 = 0.f;
    #pragma unroll
    for (int r = 0; r < 8; ++r) {
        dp0 += q[r] * wP2[r * 3 + 0];
        dp1 += q[r] * wP2[r * 3 + 1];
        dp2 += q[r] * wP2[r * 3 + 2];
    }
}

__device__ __forceinline__ void node_mlp(
    const float* __restrict__ wN1, const float* __restrict__ bN1,
    const float* __restrict__ wN2, const float* __restrict__ bN2,
    const float* hl, const float* nu, float* hn)
{
    float u[8];
    #pragma unroll
    for (int j = 0; j < 8; ++j) {
        float a = bN1[j];
        #pragma unroll
        for (int r = 0; r < 8; ++r) a += hl[r] * wN1[r * 8 + j];
        #pragma unroll
        for (int r = 0; r < 8; ++r) a += nu[r] * wN1[64 + r * 8 + j];
        u[j] = silu_f(a);
    }
    #pragma unroll
    for (int j = 0; j < 8; ++j) {
        float a = bN2[j];
        #pragma unroll
        for (int r = 0; r < 8; ++r) a += u[r] * wN2[r * 8 + j];
        hn[j] = a;
    }
}

__device__ __forceinline__ void latent_mlp(
    const float* __restrict__ tW1, const float* __restrict__ tB1,
    const float* __restrict__ tW2, const float* __restrict__ tB2,
    const float* __restrict__ fW1, const float* __restrict__ fB1,
    const float* __restrict__ fW2, const float* __restrict__ fB2,
    float* hn)
{
    float a8[8];
    #pragma unroll
    for (int j = 0; j < 8; ++j) {
        float a = tB1[j];
        #pragma unroll
        for (int r = 0; r < 8; ++r) a += hn[r] * tW1[r * 8 + j];
        a8[j] = silu_f(a);
    }
    float zz[8];
    #pragma unroll
    for (int j = 0; j < 8; ++j) {
        float a = tB2[j];
        #pragma unroll
        for (int r = 0; r < 8; ++r) a += a8[r] * tW2[r * 8 + j];
        zz[j] = a;
    }
    float b8[8];
    #pragma unroll
    for (int j = 0; j < 8; ++j) {
        float a = fB1[j];
        #pragma unroll
        for (int r = 0; r < 8; ++r) a += zz[r] * fW1[r * 8 + j];
        b8[j] = silu_f(a);
    }
    #pragma unroll
    for (int j = 0; j < 8; ++j) {
        float a = fB2[j];
        #pragma unroll
        for (int r = 0; r < 8; ++r) a += b8[r] * fW2[r * 8 + j];
        hn[j] = a;
    }
}

__global__ __launch_bounds__(256) void k_stack(
    const float* __restrict__ h0, const float* __restrict__ pos0,
    float* __restrict__ hfin,
    const float* __restrict__ ceW1, const float* __restrict__ ceB1,
    const float* __restrict__ ceW2, const float* __restrict__ ceB2,
    const float* __restrict__ cpW1, const float* __restrict__ cpB1,
    const float* __restrict__ cpW2,
    const float* __restrict__ cnW1, const float* __restrict__ cnB1,
    const float* __restrict__ cnW2, const float* __restrict__ cnB2,
    const float* __restrict__ tW1, const float* __restrict__ tB1,
    const float* __restrict__ tW2, const float* __restrict__ tB2,
    const float* __restrict__ fW1, const float* __restrict__ fB1,
    const float* __restrict__ fW2, const float* __restrict__ fB2)
{
    const int lane = threadIdx.x & 63;
    const int seg  = blockIdx.x * 4 + (threadIdx.x >> 6);
    const int base = seg * SEGOUT - 8;          // first node of this wave's window
    const int n    = base + lane;               // this lane's node

    float h[8] = {0, 0, 0, 0, 0, 0, 0, 0};
    float p0 = 0.f, p1 = 0.f, p2 = 0.f;
    if (n >= 0 && n < NTOT) {
        const float4* hp = (const float4*)(h0 + (long)n * 8);
        float4 a = hp[0], b = hp[1];
        h[0] = a.x; h[1] = a.y; h[2] = a.z; h[3] = a.w;
        h[4] = b.x; h[5] = b.y; h[6] = b.z; h[7] = b.w;
        float4 p = ((const float4*)pos0)[n];
        p0 = p.x; p1 = p.y; p2 = p.z;
    }

    const bool eR = (n >= 0) && (n + 1 < NTOT);   // edge (n, n+1) exists
    const bool eL = (n >= 1) && (n < NTOT);       // edge (n-1, n) exists

    #pragma unroll 1
    for (int li = 0; li < NLAY; ++li) {
        const float* wE1 = ceW1 + li * 136;
        const float* bE1 = ceB1 + li * 8;
        const float* wE2 = ceW2 + li * 64;
        const float* bE2 = ceB2 + li * 8;
        const float* wP1 = cpW1 + li * 64;
        const float* bP1 = cpB1 + li * 8;
        const float* wP2 = cpW2 + li * 24;
        const float* wN1 = cnW1 + li * 128;
        const float* bN1 = cnB1 + li * 8;
        const float* wN2 = cnW2 + li * 64;
        const float* bN2 = cnB2 + li * 8;

        // right neighbor = next lane's node
        float hr[8], pr0, pr1, pr2;
        #pragma unroll
        for (int j = 0; j < 8; ++j) hr[j] = __shfl_down(h[j], 1);
        pr0 = __shfl_down(p0, 1);
        pr1 = __shfl_down(p1, 1);
        pr2 = __shfl_down(p2, 1);

        float ea[8], dp0, dp1, dp2;
        edge_mlp(wE1, bE1, wE2, bE2, wP1, bP1, wP2,
                 h, hr, pr0 - p0, pr1 - p1, pr2 - p2, ea, dp0, dp1, dp2);

        // left edge of node n = previous lane's edge
        float eaL[8], dl0, dl1, dl2;
        #pragma unroll
        for (int j = 0; j < 8; ++j) eaL[j] = __shfl_up(ea[j], 1);
        dl0 = __shfl_up(dp0, 1);
        dl1 = __shfl_up(dp1, 1);
        dl2 = __shfl_up(dp2, 1);

        float nu[8];
        #pragma unroll
        for (int j = 0; j < 8; ++j)
            nu[j] = (eR ? ea[j] : 0.f) + (eL ? eaL[j] : 0.f);
        float pu0 = (eR ? dp0 : 0.f) - (eL ? dl0 : 0.f);
        float pu1 = (eR ? dp1 : 0.f) - (eL ? dl1 : 0.f);
        float pu2 = (eR ? dp2 : 0.f) - (eL ? dl2 : 0.f);

        float hn[8];
        node_mlp(wN1, bN1, wN2, bN2, h, nu, hn);

        p0 += 0.1f * pu0; p1 += 0.1f * pu1; p2 += 0.1f * pu2;

        if (li == 3) {
            latent_mlp(tW1, tB1, tW2, tB2, fW1, fB1, fW2, fB2, hn);
        }

        #pragma unroll
        for (int j = 0; j < 8; ++j) h[j] = hn[j];
    }

    // valid output = lanes 8..55 (halo 8 each side consumed by 8 layers)
    if (lane >= 8 && lane < 56 && n < NTOT) {
        float4* hd = (float4*)(hfin + (long)n * 8);
        hd[0] = make_float4(h[0], h[1], h[2], h[3]);
        hd[1] = make_float4(h[4], h[5], h[6], h[7]);
    }
}

// ---------------- Kernel 3: decode (h -> pos_out, mask_out) ---------------
// R2-proven version, verbatim.
__global__ __launch_bounds__(256) void k_decode(
    const float* __restrict__ hfin,
    const float* __restrict__ dW1, const float* __restrict__ dB1,
    const float* __restrict__ dW2, const float* __restrict__ dB2,
    const float* __restrict__ mW, const float* __restrict__ mB,
    float* __restrict__ out)
{
    __shared__ alignas(16) float sh[128 * 8];
    __shared__ alignas(16) float st1[128 * 16];
    const int tid = threadIdx.x;
    const long nb = (long)blockIdx.x * 128;

    ((float4*)sh)[tid] = ((const float4*)(hfin + nb * 8))[tid];
    __syncthreads();

    {   // t1 = silu(h @ posdec_W1 + b1): 2 threads per node, 8 cols each
        const int n = tid >> 1;
        const int c0 = (tid & 1) * 8;
        const float4* h4 = (const float4*)(sh + n * 8);
        float4 h0v = h4[0], h1v = h4[1];
        float hr[8] = {h0v.x, h0v.y, h0v.z, h0v.w, h1v.x, h1v.y, h1v.z, h1v.w};
        #pragma unroll
        for (int jj = 0; jj < 8; ++jj) {
            int j = c0 + jj;
            float a = dB1[j];
            #pragma unroll
            for (int r = 0; r < 8; ++r) a += hr[r] * dW1[r * 16 + j];
            st1[n * 16 + j] = silu_f(a);
        }
    }
    __syncthreads();

    if (tid < 222) {
        // ---- pos_out: column-stationary, 2 node-phases ----
        const int half = (tid >= 111) ? 1 : 0;
        const int j = tid - half * 111;
        float w[16];
        #pragma unroll
        for (int r = 0; r < 16; ++r) w[r] = dW2[r * 111 + j];
        const float bj = dB2[j];
        float* op = out + nb * 111 + j;
        #pragma unroll 2
        for (int n = half; n < 128; n += 2) {
            const float4* t4 = (const float4*)(st1 + n * 16);
            float4 a0 = t4[0], a1 = t4[1], a2 = t4[2], a3 = t4[3];
            float acc = bj;
            acc += a0.x * w[0] + a0.y * w[1] + a0.z * w[2] + a0.w * w[3];
            acc += a1.x * w[4] + a1.y * w[5] + a1.z * w[6] + a1.w * w[7];
            acc += a2.x * w[8] + a2.y * w[9] + a2.z * w[10] + a2.w * w[11];
            acc += a3.x * w[12] + a3.y * w[13] + a3.z * w[14] + a3.w * w[15];
            op[n * 111] = acc;
        }
        // ---- mask_out: column-stationary, 6 node-phases ----
        const int g6 = tid / 37;      // 0..5
        const int j2 = tid - g6 * 37;
        float wm[8];
        #pragma unroll
        for (int r = 0; r < 8; ++r) wm[r] = mW[r * 37 + j2];
        const float bm = mB[j2];
        float* omp_ = out + (long)NTOT * 111 + nb * 37 + j2;
        #pragma unroll 1
        for (int n = g6; n < 128; n += 6) {
            const float4* h4 = (const float4*)(sh + n * 8);
            float4 h0v = h4[0], h1v = h4[1];
            float acc = bm;
            acc += h0v.x * wm[0] + h0v.y * wm[1] + h0v.z * wm[2] + h0v.w * wm[3];
            acc += h1v.x * wm[4] + h1v.y * wm[5] + h1v.z * wm[6] + h1v.w * wm[7];
            omp_[n * 37] = acc;
        }
    }
}

extern "C" void kernel_launch(void* const* d_in, const int* in_sizes, int n_in,
                              void* d_out, int out_size, void* d_ws, size_t ws_size,
                              hipStream_t stream) {
    const float* ap     = (const float*)d_in[0];
    const float* amask  = (const float*)d_in[1];
    const float* embW   = (const float*)d_in[2];
    const float* embB   = (const float*)d_in[3];
    const float* peW1   = (const float*)d_in[4];
    const float* peB1   = (const float*)d_in[5];
    const float* peW2   = (const float*)d_in[6];
    const float* peB2   = (const float*)d_in[7];
    const float* ceW1   = (const float*)d_in[8];
    const float* ceB1   = (const float*)d_in[9];
    const float* ceW2   = (const float*)d_in[10];
    const float* ceB2   = (const float*)d_in[11];
    const float* cpW1   = (const float*)d_in[12];
    const float* cpB1   = (const float*)d_in[13];
    const float* cpW2   = (const float*)d_in[14];
    const float* cnW1   = (const float*)d_in[15];
    const float* cnB1   = (const float*)d_in[16];
    const float* cnW2   = (const float*)d_in[17];
    const float* cnB2   = (const float*)d_in[18];
    const float* tW1    = (const float*)d_in[19];
    const float* tB1    = (const float*)d_in[20];
    const float* tW2    = (const float*)d_in[21];
    const float* tB2    = (const float*)d_in[22];
    const float* fW1    = (const float*)d_in[23];
    const float* fB1    = (const float*)d_in[24];
    const float* fW2    = (const float*)d_in[25];
    const float* fB2    = (const float*)d_in[26];
    const float* dW1    = (const float*)d_in[27];
    const float* dB1    = (const float*)d_in[28];
    const float* dW2    = (const float*)d_in[29];
    const float* dB2    = (const float*)d_in[30];
    const float* mW     = (const float*)d_in[31];
    const float* mB     = (const float*)d_in[32];

    float* h0   = (float*)d_ws;
    float* pos0 = h0 + (size_t)NTOT * 8;
    float* hfin = pos0 + (size_t)NTOT * 4;
    float* out  = (float*)d_out;

    k_encode<<<NTOT / 256, 256, 0, stream>>>(ap, amask, embW, embB,
                                             peW1, peB1, peW2, peB2, h0, pos0);
    const int nblk = (NSEG + 3) / 4;   // 4 waves per 256-thread block
    k_stack<<<nblk, 256, 0, stream>>>(
        h0, pos0, hfin,
        ceW1, ceB1, ceW2, ceB2, cpW1, cpB1, cpW2,
        cnW1, cnB1, cnW2, cnB2,
        tW1, tB1, tW2, tB2, fW1, fB1, fW2, fB2);
    k_decode<<<NTOT / 128, 256, 0, stream>>>(hfin, dW1, dB1, dW2, dB2, mW, mB, out);
}

// Round 8
// 472.259 us; speedup vs baseline: 1.4152x; 1.4152x over previous
//
#include <hip/hip_runtime.h>

#define NTOT 262144   // B*L
#define NLAY 8
#define SEGOUT 48     // useful nodes per 64-lane wave (64 nodes incl. 8+8 halo)
#define NSEG ((NTOT + SEGOUT - 1) / SEGOUT)   // 5462

// silu via v_rcp_f32: harness compiles WITHOUT fast-math, so 1.0f/x emits the
// full IEEE divide expansion (~10 VALU ops). v_rcp is 1 op, ~1 ulp — noise vs
// the 2.4e-4 absmax budget. Same for v_sqrt.
__device__ __forceinline__ float silu_f(float x) {
    return x * __builtin_amdgcn_rcpf(1.0f + __expf(-x));
}

// ---------------- Kernel 1: encode  (mask/pos -> h0, pos0) ----------------
// R2-proven version, verbatim. 64 nodes/block, 256 threads, block-wide float4
// staging, quad-split reduce. PROVEN twice (R3, R7) that any non-coalesced
// rewrite loses 4-10x: R7's direct-global version fetched 938MB (6x ideal)
// from L1 thrash at 148B lane stride and ran 311us.
__global__ __launch_bounds__(256) void k_encode(
    const float* __restrict__ ap, const float* __restrict__ amask,
    const float* __restrict__ embW, const float* __restrict__ embB,
    const float* __restrict__ peW1, const float* __restrict__ peB1,
    const float* __restrict__ peW2, const float* __restrict__ peB2,
    float* __restrict__ h0, float* __restrict__ pos0)
{
    __shared__ alignas(16) float sM[64 * 37];
    __shared__ alignas(16) float sA[64 * 111];
    __shared__ alignas(16) float sW[37 * 8];     // embW staged (296 floats)
    const int tid = threadIdx.x;
    const long nb = (long)blockIdx.x * 64;

    if (tid < 74) ((float4*)sW)[tid] = ((const float4*)embW)[tid];
    const float4* gm = (const float4*)(amask + nb * 37);
    float4* sm4 = (float4*)sM;
    #pragma unroll 1
    for (int i = tid; i < 64 * 37 / 4; i += 256) sm4[i] = gm[i];
    const float4* ga = (const float4*)(ap + nb * 111);
    float4* sa4 = (float4*)sA;
    #pragma unroll 1
    for (int i = tid; i < 64 * 111 / 4; i += 256) sa4[i] = ga[i];
    __syncthreads();

    const int n = tid >> 2;          // node within block
    const int p = tid & 3;           // quad lane
    const int k0 = p * 10;
    const int k1 = (p == 3) ? 37 : k0 + 10;

    const float* mrow = sM + n * 37;
    const float* arow = sA + n * 111;
    float hacc[8] = {0, 0, 0, 0, 0, 0, 0, 0};
    float ps0 = 0.f, ps1 = 0.f, ps2 = 0.f, msum = 0.f;
    #pragma unroll 1
    for (int k = k0; k < k1; ++k) {
        float mv = mrow[k];
        msum += mv;
        const float4* wr = (const float4*)(sW + k * 8);
        float4 w0 = wr[0], w1 = wr[1];
        hacc[0] += mv * w0.x; hacc[1] += mv * w0.y;
        hacc[2] += mv * w0.z; hacc[3] += mv * w0.w;
        hacc[4] += mv * w1.x; hacc[5] += mv * w1.y;
        hacc[6] += mv * w1.z; hacc[7] += mv * w1.w;
        ps0 += mv * arow[k * 3 + 0];
        ps1 += mv * arow[k * 3 + 1];
        ps2 += mv * arow[k * 3 + 2];
    }
    #pragma unroll
    for (int m = 1; m <= 2; m <<= 1) {
        msum += __shfl_xor(msum, m);
        ps0 += __shfl_xor(ps0, m);
        ps1 += __shfl_xor(ps1, m);
        ps2 += __shfl_xor(ps2, m);
        #pragma unroll
        for (int j = 0; j < 8; ++j) hacc[j] += __shfl_xor(hacc[j], m);
    }

    float inv = __builtin_amdgcn_rcpf(msum + 1e-8f);
    float mp0 = ps0 * inv, mp1 = ps1 * inv, mp2 = ps2 * inv;
    float q[8];
    #pragma unroll
    for (int j = 0; j < 8; ++j) {
        float a = peB1[j];
        a += mp0 * peW1[0 * 8 + j];
        a += mp1 * peW1[1 * 8 + j];
        a += mp2 * peW1[2 * 8 + j];
        q[j] = silu_f(a);
    }
    #pragma unroll
    for (int j = 0; j < 8; ++j) {
        float a = peB2[j] + embB[j];
        #pragma unroll
        for (int r = 0; r < 8; ++r) a += q[r] * peW2[r * 8 + j];
        hacc[j] += a;
    }
    const long g = nb + n;
    if (p == 0) ((float4*)(h0 + g * 8))[0] = make_float4(hacc[0], hacc[1], hacc[2], hacc[3]);
    if (p == 1) ((float4*)(h0 + g * 8))[1] = make_float4(hacc[4], hacc[5], hacc[6], hacc[7]);
    if (p == 2) ((float4*)pos0)[g] = make_float4(mp0, mp1, mp2, 0.f);
}

// ---------------- Kernel 2: fused 8-layer SE3 stack + mid latent ----------
// R2-proven structure. Wave-autonomous, 1 node/lane, 8+8 halo, __shfl
// exchange, NO LDS, NO barriers. Weights via global scalar path (s_load) —
// do NOT stage in LDS (R5: VGPR 48->224, 10% occ).
// R8 change: layer loop unrolled x2 so the scheduler can hoist layer li+1's
// s_load weight stream above layer li's tail FMAs (weights are const/restrict,
// no deps) — targets the ~200cyc first-use s_load stall per layer.
__device__ __forceinline__ void edge_mlp(
    const float* __restrict__ wE1, const float* __restrict__ bE1,
    const float* __restrict__ wE2, const float* __restrict__ bE2,
    const float* __restrict__ wP1, const float* __restrict__ bP1,
    const float* __restrict__ wP2,
    const float* hl, const float* hr, float r0, float r1, float r2,
    float* ea, float& dp0, float& dp1, float& dp2)
{
    float dist = __builtin_amdgcn_sqrtf(r0 * r0 + r1 * r1 + r2 * r2);
    float t1[8];
    #pragma unroll
    for (int j = 0; j < 8; ++j) {
        float a = bE1[j];
        #pragma unroll
        for (int r = 0; r < 8; ++r) a += hl[r] * wE1[r * 8 + j];
        #pragma unroll
        for (int r = 0; r < 8; ++r) a += hr[r] * wE1[64 + r * 8 + j];
        a += dist * wE1[128 + j];
        t1[j] = silu_f(a);
    }
    #pragma unroll
    for (int j = 0; j < 8; ++j) {
        float a = bE2[j];
        #pragma unroll
        for (int r = 0; r < 8; ++r) a += t1[r] * wE2[r * 8 + j];
        ea[j] = a;
    }
    float q[8];
    #pragma unroll
    for (int j = 0; j < 8; ++j) {
        float a = bP1[j];
        #pragma unroll
        for (int r = 0; r < 8; ++r) a += ea[r] * wP1[r * 8 + j];
        q[j] = silu_f(a);
    }
    dp0 = 0.f; dp1 = 0.f; dp2 = 0.f;
    #pragma unroll
    for (int r = 0; r < 8; ++r) {
        dp0 += q[r] * wP2[r * 3 + 0];
        dp1 += q[r] * wP2[r * 3 + 1];
        dp2 += q[r] * wP2[r * 3 + 2];
    }
}

__device__ __forceinline__ void node_mlp(
    const float* __restrict__ wN1, const float* __restrict__ bN1,
    const float* __restrict__ wN2, const float* __restrict__ bN2,
    const float* hl, const float* nu, float* hn)
{
    float u[8];
    #pragma unroll
    for (int j = 0; j < 8; ++j) {
        float a = bN1[j];
        #pragma unroll
        for (int r = 0; r < 8; ++r) a += hl[r] * wN1[r * 8 + j];
        #pragma unroll
        for (int r = 0; r < 8; ++r) a += nu[r] * wN1[64 + r * 8 + j];
        u[j] = silu_f(a);
    }
    #pragma unroll
    for (int j = 0; j < 8; ++j) {
        float a = bN2[j];
        #pragma unroll
        for (int r = 0; r < 8; ++r) a += u[r] * wN2[r * 8 + j];
        hn[j] = a;
    }
}

__device__ __forceinline__ void latent_mlp(
    const float* __restrict__ tW1, const float* __restrict__ tB1,
    const float* __restrict__ tW2, const float* __restrict__ tB2,
    const float* __restrict__ fW1, const float* __restrict__ fB1,
    const float* __restrict__ fW2, const float* __restrict__ fB2,
    float* hn)
{
    float a8[8];
    #pragma unroll
    for (int j = 0; j < 8; ++j) {
        float a = tB1[j];
        #pragma unroll
        for (int r = 0; r < 8; ++r) a += hn[r] * tW1[r * 8 + j];
        a8[j] = silu_f(a);
    }
    float zz[8];
    #pragma unroll
    for (int j = 0; j < 8; ++j) {
        float a = tB2[j];
        #pragma unroll
        for (int r = 0; r < 8; ++r) a += a8[r] * tW2[r * 8 + j];
        zz[j] = a;
    }
    float b8[8];
    #pragma unroll
    for (int j = 0; j < 8; ++j) {
        float a = fB1[j];
        #pragma unroll
        for (int r = 0; r < 8; ++r) a += zz[r] * fW1[r * 8 + j];
        b8[j] = silu_f(a);
    }
    #pragma unroll
    for (int j = 0; j < 8; ++j) {
        float a = fB2[j];
        #pragma unroll
        for (int r = 0; r < 8; ++r) a += b8[r] * fW2[r * 8 + j];
        hn[j] = a;
    }
}

__global__ __launch_bounds__(256) void k_stack(
    const float* __restrict__ h0, const float* __restrict__ pos0,
    float* __restrict__ hfin,
    const float* __restrict__ ceW1, const float* __restrict__ ceB1,
    const float* __restrict__ ceW2, const float* __restrict__ ceB2,
    const float* __restrict__ cpW1, const float* __restrict__ cpB1,
    const float* __restrict__ cpW2,
    const float* __restrict__ cnW1, const float* __restrict__ cnB1,
    const float* __restrict__ cnW2, const float* __restrict__ cnB2,
    const float* __restrict__ tW1, const float* __restrict__ tB1,
    const float* __restrict__ tW2, const float* __restrict__ tB2,
    const float* __restrict__ fW1, const float* __restrict__ fB1,
    const float* __restrict__ fW2, const float* __restrict__ fB2)
{
    const int lane = threadIdx.x & 63;
    const int seg  = blockIdx.x * 4 + (threadIdx.x >> 6);
    const int base = seg * SEGOUT - 8;          // first node of this wave's window
    const int n    = base + lane;               // this lane's node

    float h[8] = {0, 0, 0, 0, 0, 0, 0, 0};
    float p0 = 0.f, p1 = 0.f, p2 = 0.f;
    if (n >= 0 && n < NTOT) {
        const float4* hp = (const float4*)(h0 + (long)n * 8);
        float4 a = hp[0], b = hp[1];
        h[0] = a.x; h[1] = a.y; h[2] = a.z; h[3] = a.w;
        h[4] = b.x; h[5] = b.y; h[6] = b.z; h[7] = b.w;
        float4 p = ((const float4*)pos0)[n];
        p0 = p.x; p1 = p.y; p2 = p.z;
    }

    const bool eR = (n >= 0) && (n + 1 < NTOT);   // edge (n, n+1) exists
    const bool eL = (n >= 1) && (n < NTOT);       // edge (n-1, n) exists

    #pragma unroll 2
    for (int li = 0; li < NLAY; ++li) {
        const float* wE1 = ceW1 + li * 136;
        const float* bE1 = ceB1 + li * 8;
        const float* wE2 = ceW2 + li * 64;
        const float* bE2 = ceB2 + li * 8;
        const float* wP1 = cpW1 + li * 64;
        const float* bP1 = cpB1 + li * 8;
        const float* wP2 = cpW2 + li * 24;
        const float* wN1 = cnW1 + li * 128;
        const float* bN1 = cnB1 + li * 8;
        const float* wN2 = cnW2 + li * 64;
        const float* bN2 = cnB2 + li * 8;

        // right neighbor = next lane's node
        float hr[8], pr0, pr1, pr2;
        #pragma unroll
        for (int j = 0; j < 8; ++j) hr[j] = __shfl_down(h[j], 1);
        pr0 = __shfl_down(p0, 1);
        pr1 = __shfl_down(p1, 1);
        pr2 = __shfl_down(p2, 1);

        float ea[8], dp0, dp1, dp2;
        edge_mlp(wE1, bE1, wE2, bE2, wP1, bP1, wP2,
                 h, hr, pr0 - p0, pr1 - p1, pr2 - p2, ea, dp0, dp1, dp2);

        // left edge of node n = previous lane's edge
        float eaL[8], dl0, dl1, dl2;
        #pragma unroll
        for (int j = 0; j < 8; ++j) eaL[j] = __shfl_up(ea[j], 1);
        dl0 = __shfl_up(dp0, 1);
        dl1 = __shfl_up(dp1, 1);
        dl2 = __shfl_up(dp2, 1);

        float nu[8];
        #pragma unroll
        for (int j = 0; j < 8; ++j)
            nu[j] = (eR ? ea[j] : 0.f) + (eL ? eaL[j] : 0.f);
        float pu0 = (eR ? dp0 : 0.f) - (eL ? dl0 : 0.f);
        float pu1 = (eR ? dp1 : 0.f) - (eL ? dl1 : 0.f);
        float pu2 = (eR ? dp2 : 0.f) - (eL ? dl2 : 0.f);

        float hn[8];
        node_mlp(wN1, bN1, wN2, bN2, h, nu, hn);

        p0 += 0.1f * pu0; p1 += 0.1f * pu1; p2 += 0.1f * pu2;

        if (li == 3) {
            latent_mlp(tW1, tB1, tW2, tB2, fW1, fB1, fW2, fB2, hn);
        }

        #pragma unroll
        for (int j = 0; j < 8; ++j) h[j] = hn[j];
    }

    // valid output = lanes 8..55 (halo 8 each side consumed by 8 layers)
    if (lane >= 8 && lane < 56 && n < NTOT) {
        float4* hd = (float4*)(hfin + (long)n * 8);
        hd[0] = make_float4(h[0], h[1], h[2], h[3]);
        hd[1] = make_float4(h[4], h[5], h[6], h[7]);
    }
}

// ---------------- Kernel 3: decode (h -> pos_out, mask_out) ---------------
// R2-proven version, verbatim.
__global__ __launch_bounds__(256) void k_decode(
    const float* __restrict__ hfin,
    const float* __restrict__ dW1, const float* __restrict__ dB1,
    const float* __restrict__ dW2, const float* __restrict__ dB2,
    const float* __restrict__ mW, const float* __restrict__ mB,
    float* __restrict__ out)
{
    __shared__ alignas(16) float sh[128 * 8];
    __shared__ alignas(16) float st1[128 * 16];
    const int tid = threadIdx.x;
    const long nb = (long)blockIdx.x * 128;

    ((float4*)sh)[tid] = ((const float4*)(hfin + nb * 8))[tid];
    __syncthreads();

    {   // t1 = silu(h @ posdec_W1 + b1): 2 threads per node, 8 cols each
        const int n = tid >> 1;
        const int c0 = (tid & 1) * 8;
        const float4* h4 = (const float4*)(sh + n * 8);
        float4 h0v = h4[0], h1v = h4[1];
        float hr[8] = {h0v.x, h0v.y, h0v.z, h0v.w, h1v.x, h1v.y, h1v.z, h1v.w};
        #pragma unroll
        for (int jj = 0; jj < 8; ++jj) {
            int j = c0 + jj;
            float a = dB1[j];
            #pragma unroll
            for (int r = 0; r < 8; ++r) a += hr[r] * dW1[r * 16 + j];
            st1[n * 16 + j] = silu_f(a);
        }
    }
    __syncthreads();

    if (tid < 222) {
        // ---- pos_out: column-stationary, 2 node-phases ----
        const int half = (tid >= 111) ? 1 : 0;
        const int j = tid - half * 111;
        float w[16];
        #pragma unroll
        for (int r = 0; r < 16; ++r) w[r] = dW2[r * 111 + j];
        const float bj = dB2[j];
        float* op = out + nb * 111 + j;
        #pragma unroll 2
        for (int n = half; n < 128; n += 2) {
            const float4* t4 = (const float4*)(st1 + n * 16);
            float4 a0 = t4[0], a1 = t4[1], a2 = t4[2], a3 = t4[3];
            float acc = bj;
            acc += a0.x * w[0] + a0.y * w[1] + a0.z * w[2] + a0.w * w[3];
            acc += a1.x * w[4] + a1.y * w[5] + a1.z * w[6] + a1.w * w[7];
            acc += a2.x * w[8] + a2.y * w[9] + a2.z * w[10] + a2.w * w[11];
            acc += a3.x * w[12] + a3.y * w[13] + a3.z * w[14] + a3.w * w[15];
            op[n * 111] = acc;
        }
        // ---- mask_out: column-stationary, 6 node-phases ----
        const int g6 = tid / 37;      // 0..5
        const int j2 = tid - g6 * 37;
        float wm[8];
        #pragma unroll
        for (int r = 0; r < 8; ++r) wm[r] = mW[r * 37 + j2];
        const float bm = mB[j2];
        float* omp_ = out + (long)NTOT * 111 + nb * 37 + j2;
        #pragma unroll 1
        for (int n = g6; n < 128; n += 6) {
            const float4* h4 = (const float4*)(sh + n * 8);
            float4 h0v = h4[0], h1v = h4[1];
            float acc = bm;
            acc += h0v.x * wm[0] + h0v.y * wm[1] + h0v.z * wm[2] + h0v.w * wm[3];
            acc += h1v.x * wm[4] + h1v.y * wm[5] + h1v.z * wm[6] + h1v.w * wm[7];
            omp_[n * 37] = acc;
        }
    }
}

extern "C" void kernel_launch(void* const* d_in, const int* in_sizes, int n_in,
                              void* d_out, int out_size, void* d_ws, size_t ws_size,
                              hipStream_t stream) {
    const float* ap     = (const float*)d_in[0];
    const float* amask  = (const float*)d_in[1];
    const float* embW   = (const float*)d_in[2];
    const float* embB   = (const float*)d_in[3];
    const float* peW1   = (const float*)d_in[4];
    const float* peB1   = (const float*)d_in[5];
    const float* peW2   = (const float*)d_in[6];
    const float* peB2   = (const float*)d_in[7];
    const float* ceW1   = (const float*)d_in[8];
    const float* ceB1   = (const float*)d_in[9];
    const float* ceW2   = (const float*)d_in[10];
    const float* ceB2   = (const float*)d_in[11];
    const float* cpW1   = (const float*)d_in[12];
    const float* cpB1   = (const float*)d_in[13];
    const float* cpW2   = (const float*)d_in[14];
    const float* cnW1   = (const float*)d_in[15];
    const float* cnB1   = (const float*)d_in[16];
    const float* cnW2   = (const float*)d_in[17];
    const float* cnB2   = (const float*)d_in[18];
    const float* tW1    = (const float*)d_in[19];
    const float* tB1    = (const float*)d_in[20];
    const float* tW2    = (const float*)d_in[21];
    const float* tB2    = (const float*)d_in[22];
    const float* fW1    = (const float*)d_in[23];
    const float* fB1    = (const float*)d_in[24];
    const float* fW2    = (const float*)d_in[25];
    const float* fB2    = (const float*)d_in[26];
    const float* dW1    = (const float*)d_in[27];
    const float* dB1    = (const float*)d_in[28];
    const float* dW2    = (const float*)d_in[29];
    const float* dB2    = (const float*)d_in[30];
    const float* mW     = (const float*)d_in[31];
    const float* mB     = (const float*)d_in[32];

    float* h0   = (float*)d_ws;
    float* pos0 = h0 + (size_t)NTOT * 8;
    float* hfin = pos0 + (size_t)NTOT * 4;
    float* out  = (float*)d_out;

    k_encode<<<NTOT / 64, 256, 0, stream>>>(ap, amask, embW, embB,
                                            peW1, peB1, peW2, peB2, h0, pos0);
    const int nblk = (NSEG + 3) / 4;   // 4 waves per 256-thread block
    k_stack<<<nblk, 256, 0, stream>>>(
        h0, pos0, hfin,
        ceW1, ceB1, ceW2, ceB2, cpW1, cpB1, cpW2,
        cnW1, cnB1, cnW2, cnB2,
        tW1, tB1, tW2, tB2, fW1, fB1, fW2, fB2);
    k_decode<<<NTOT / 128, 256, 0, stream>>>(hfin, dW1, dB1, dW2, dB2, mW, mB, out);
}

// Round 9
// 449.590 us; speedup vs baseline: 1.4866x; 1.0504x over previous
//
#include <hip/hip_runtime.h>

#define NTOT 262144   // B*L
#define NLAY 8
#define SEG4 56       // useful nodes per wave in a 4-layer kernel (64 incl. 4+4 halo)
#define NSEG4 ((NTOT + SEG4 - 1) / SEG4)   // 4682
#define NBLK4 ((NSEG4 + 3) / 4)            // 1171

// silu via v_rcp_f32: harness compiles WITHOUT fast-math, so 1.0f/x emits the
// full IEEE divide expansion (~10 VALU ops). v_rcp is 1 op, ~1 ulp — noise vs
// the 2.4e-4 absmax budget. Same for v_sqrt.
__device__ __forceinline__ float silu_f(float x) {
    return x * __builtin_amdgcn_rcpf(1.0f + __expf(-x));
}

// ---------------- Kernel 1: encode  (mask/pos -> h0, pos0) ----------------
// R2-proven version, verbatim. 64 nodes/block, 256 threads, block-wide float4
// staging, quad-split reduce. PROVEN twice (R3, R7) that non-coalesced
// rewrites lose 4-10x (R7 direct-global: 938MB fetch, 311us).
__global__ __launch_bounds__(256) void k_encode(
    const float* __restrict__ ap, const float* __restrict__ amask,
    const float* __restrict__ embW, const float* __restrict__ embB,
    const float* __restrict__ peW1, const float* __restrict__ peB1,
    const float* __restrict__ peW2, const float* __restrict__ peB2,
    float* __restrict__ h0, float* __restrict__ pos0)
{
    __shared__ alignas(16) float sM[64 * 37];
    __shared__ alignas(16) float sA[64 * 111];
    __shared__ alignas(16) float sW[37 * 8];     // embW staged (296 floats)
    const int tid = threadIdx.x;
    const long nb = (long)blockIdx.x * 64;

    if (tid < 74) ((float4*)sW)[tid] = ((const float4*)embW)[tid];
    const float4* gm = (const float4*)(amask + nb * 37);
    float4* sm4 = (float4*)sM;
    #pragma unroll 1
    for (int i = tid; i < 64 * 37 / 4; i += 256) sm4[i] = gm[i];
    const float4* ga = (const float4*)(ap + nb * 111);
    float4* sa4 = (float4*)sA;
    #pragma unroll 1
    for (int i = tid; i < 64 * 111 / 4; i += 256) sa4[i] = ga[i];
    __syncthreads();

    const int n = tid >> 2;          // node within block
    const int p = tid & 3;           // quad lane
    const int k0 = p * 10;
    const int k1 = (p == 3) ? 37 : k0 + 10;

    const float* mrow = sM + n * 37;
    const float* arow = sA + n * 111;
    float hacc[8] = {0, 0, 0, 0, 0, 0, 0, 0};
    float ps0 = 0.f, ps1 = 0.f, ps2 = 0.f, msum = 0.f;
    #pragma unroll 1
    for (int k = k0; k < k1; ++k) {
        float mv = mrow[k];
        msum += mv;
        const float4* wr = (const float4*)(sW + k * 8);
        float4 w0 = wr[0], w1 = wr[1];
        hacc[0] += mv * w0.x; hacc[1] += mv * w0.y;
        hacc[2] += mv * w0.z; hacc[3] += mv * w0.w;
        hacc[4] += mv * w1.x; hacc[5] += mv * w1.y;
        hacc[6] += mv * w1.z; hacc[7] += mv * w1.w;
        ps0 += mv * arow[k * 3 + 0];
        ps1 += mv * arow[k * 3 + 1];
        ps2 += mv * arow[k * 3 + 2];
    }
    #pragma unroll
    for (int m = 1; m <= 2; m <<= 1) {
        msum += __shfl_xor(msum, m);
        ps0 += __shfl_xor(ps0, m);
        ps1 += __shfl_xor(ps1, m);
        ps2 += __shfl_xor(ps2, m);
        #pragma unroll
        for (int j = 0; j < 8; ++j) hacc[j] += __shfl_xor(hacc[j], m);
    }

    float inv = __builtin_amdgcn_rcpf(msum + 1e-8f);
    float mp0 = ps0 * inv, mp1 = ps1 * inv, mp2 = ps2 * inv;
    float q[8];
    #pragma unroll
    for (int j = 0; j < 8; ++j) {
        float a = peB1[j];
        a += mp0 * peW1[0 * 8 + j];
        a += mp1 * peW1[1 * 8 + j];
        a += mp2 * peW1[2 * 8 + j];
        q[j] = silu_f(a);
    }
    #pragma unroll
    for (int j = 0; j < 8; ++j) {
        float a = peB2[j] + embB[j];
        #pragma unroll
        for (int r = 0; r < 8; ++r) a += q[r] * peW2[r * 8 + j];
        hacc[j] += a;
    }
    const long g = nb + n;
    if (p == 0) ((float4*)(h0 + g * 8))[0] = make_float4(hacc[0], hacc[1], hacc[2], hacc[3]);
    if (p == 1) ((float4*)(h0 + g * 8))[1] = make_float4(hacc[4], hacc[5], hacc[6], hacc[7]);
    if (p == 2) ((float4*)pos0)[g] = make_float4(mp0, mp1, mp2, 0.f);
}

// ---------------- helpers for the SE3 stack (R2-proven, verbatim) --------
__device__ __forceinline__ void edge_mlp(
    const float* __restrict__ wE1, const float* __restrict__ bE1,
    const float* __restrict__ wE2, const float* __restrict__ bE2,
    const float* __restrict__ wP1, const float* __restrict__ bP1,
    const float* __restrict__ wP2,
    const float* hl, const float* hr, float r0, float r1, float r2,
    float* ea, float& dp0, float& dp1, float& dp2)
{
    float dist = __builtin_amdgcn_sqrtf(r0 * r0 + r1 * r1 + r2 * r2);
    float t1[8];
    #pragma unroll
    for (int j = 0; j < 8; ++j) {
        float a = bE1[j];
        #pragma unroll
        for (int r = 0; r < 8; ++r) a += hl[r] * wE1[r * 8 + j];
        #pragma unroll
        for (int r = 0; r < 8; ++r) a += hr[r] * wE1[64 + r * 8 + j];
        a += dist * wE1[128 + j];
        t1[j] = silu_f(a);
    }
    #pragma unroll
    for (int j = 0; j < 8; ++j) {
        float a = bE2[j];
        #pragma unroll
        for (int r = 0; r < 8; ++r) a += t1[r] * wE2[r * 8 + j];
        ea[j] = a;
    }
    float q[8];
    #pragma unroll
    for (int j = 0; j < 8; ++j) {
        float a = bP1[j];
        #pragma unroll
        for (int r = 0; r < 8; ++r) a += ea[r] * wP1[r * 8 + j];
        q[j] = silu_f(a);
    }
    dp0 = 0.f; dp1 = 0.f; dp2 = 0.f;
    #pragma unroll
    for (int r = 0; r < 8; ++r) {
        dp0 += q[r] * wP2[r * 3 + 0];
        dp1 += q[r] * wP2[r * 3 + 1];
        dp2 += q[r] * wP2[r * 3 + 2];
    }
}

__device__ __forceinline__ void node_mlp(
    const float* __restrict__ wN1, const float* __restrict__ bN1,
    const float* __restrict__ wN2, const float* __restrict__ bN2,
    const float* hl, const float* nu, float* hn)
{
    float u[8];
    #pragma unroll
    for (int j = 0; j < 8; ++j) {
        float a = bN1[j];
        #pragma unroll
        for (int r = 0; r < 8; ++r) a += hl[r] * wN1[r * 8 + j];
        #pragma unroll
        for (int r = 0; r < 8; ++r) a += nu[r] * wN1[64 + r * 8 + j];
        u[j] = silu_f(a);
    }
    #pragma unroll
    for (int j = 0; j < 8; ++j) {
        float a = bN2[j];
        #pragma unroll
        for (int r = 0; r < 8; ++r) a += u[r] * wN2[r * 8 + j];
        hn[j] = a;
    }
}

__device__ __forceinline__ void latent_mlp(
    const float* __restrict__ tW1, const float* __restrict__ tB1,
    const float* __restrict__ tW2, const float* __restrict__ tB2,
    const float* __restrict__ fW1, const float* __restrict__ fB1,
    const float* __restrict__ fW2, const float* __restrict__ fB2,
    float* hn)
{
    float a8[8];
    #pragma unroll
    for (int j = 0; j < 8; ++j) {
        float a = tB1[j];
        #pragma unroll
        for (int r = 0; r < 8; ++r) a += hn[r] * tW1[r * 8 + j];
        a8[j] = silu_f(a);
    }
    float zz[8];
    #pragma unroll
    for (int j = 0; j < 8; ++j) {
        float a = tB2[j];
        #pragma unroll
        for (int r = 0; r < 8; ++r) a += a8[r] * tW2[r * 8 + j];
        zz[j] = a;
    }
    float b8[8];
    #pragma unroll
    for (int j = 0; j < 8; ++j) {
        float a = fB1[j];
        #pragma unroll
        for (int r = 0; r < 8; ++r) a += zz[r] * fW1[r * 8 + j];
        b8[j] = silu_f(a);
    }
    #pragma unroll
    for (int j = 0; j < 8; ++j) {
        float a = fB2[j];
        #pragma unroll
        for (int r = 0; r < 8; ++r) a += b8[r] * fW2[r * 8 + j];
        hn[j] = a;
    }
}

// -------- Kernel 2: 4-layer SE3 stack slice (launched twice) -------------
// R9 change: stack split into two 4-layer kernels. Halo shrinks 8->4 per side
// -> useful lanes 56/64 (87.5%) vs 48/64 (75%): -14% stack compute. Everything
// inside the layer loop is R2-verbatim (unroll 1 — R8 proved unroll 2 doubles
// VALU work; weights on scalar path — R5 proved LDS weights blow VGPRs).
// do_latent: apply tol/froml MLP after global layer 3 (kernel A only).
// do_pos: store updated pos (kernel A only; B's pos is dead and storing it
// would race with other blocks' halo reads of pin).
__global__ __launch_bounds__(256) void k_stack4(
    const float* __restrict__ hin, const float* __restrict__ pin,
    float* __restrict__ hout, float* __restrict__ pout,
    const int l0, const int do_latent, const int do_pos,
    const float* __restrict__ ceW1, const float* __restrict__ ceB1,
    const float* __restrict__ ceW2, const float* __restrict__ ceB2,
    const float* __restrict__ cpW1, const float* __restrict__ cpB1,
    const float* __restrict__ cpW2,
    const float* __restrict__ cnW1, const float* __restrict__ cnB1,
    const float* __restrict__ cnW2, const float* __restrict__ cnB2,
    const float* __restrict__ tW1, const float* __restrict__ tB1,
    const float* __restrict__ tW2, const float* __restrict__ tB2,
    const float* __restrict__ fW1, const float* __restrict__ fB1,
    const float* __restrict__ fW2, const float* __restrict__ fB2)
{
    const int lane = threadIdx.x & 63;
    const int seg  = blockIdx.x * 4 + (threadIdx.x >> 6);
    const int base = seg * SEG4 - 4;            // first node of this wave's window
    const int n    = base + lane;               // this lane's node

    float h[8] = {0, 0, 0, 0, 0, 0, 0, 0};
    float p0 = 0.f, p1 = 0.f, p2 = 0.f;
    if (n >= 0 && n < NTOT) {
        const float4* hp = (const float4*)(hin + (long)n * 8);
        float4 a = hp[0], b = hp[1];
        h[0] = a.x; h[1] = a.y; h[2] = a.z; h[3] = a.w;
        h[4] = b.x; h[5] = b.y; h[6] = b.z; h[7] = b.w;
        float4 p = ((const float4*)pin)[n];
        p0 = p.x; p1 = p.y; p2 = p.z;
    }

    const bool eR = (n >= 0) && (n + 1 < NTOT);   // edge (n, n+1) exists
    const bool eL = (n >= 1) && (n < NTOT);       // edge (n-1, n) exists

    #pragma unroll 1
    for (int ii = 0; ii < 4; ++ii) {
        const int li = l0 + ii;
        const float* wE1 = ceW1 + li * 136;
        const float* bE1 = ceB1 + li * 8;
        const float* wE2 = ceW2 + li * 64;
        const float* bE2 = ceB2 + li * 8;
        const float* wP1 = cpW1 + li * 64;
        const float* bP1 = cpB1 + li * 8;
        const float* wP2 = cpW2 + li * 24;
        const float* wN1 = cnW1 + li * 128;
        const float* bN1 = cnB1 + li * 8;
        const float* wN2 = cnW2 + li * 64;
        const float* bN2 = cnB2 + li * 8;

        // right neighbor = next lane's node
        float hr[8], pr0, pr1, pr2;
        #pragma unroll
        for (int j = 0; j < 8; ++j) hr[j] = __shfl_down(h[j], 1);
        pr0 = __shfl_down(p0, 1);
        pr1 = __shfl_down(p1, 1);
        pr2 = __shfl_down(p2, 1);

        float ea[8], dp0, dp1, dp2;
        edge_mlp(wE1, bE1, wE2, bE2, wP1, bP1, wP2,
                 h, hr, pr0 - p0, pr1 - p1, pr2 - p2, ea, dp0, dp1, dp2);

        // left edge of node n = previous lane's edge
        float eaL[8], dl0, dl1, dl2;
        #pragma unroll
        for (int j = 0; j < 8; ++j) eaL[j] = __shfl_up(ea[j], 1);
        dl0 = __shfl_up(dp0, 1);
        dl1 = __shfl_up(dp1, 1);
        dl2 = __shfl_up(dp2, 1);

        float nu[8];
        #pragma unroll
        for (int j = 0; j < 8; ++j)
            nu[j] = (eR ? ea[j] : 0.f) + (eL ? eaL[j] : 0.f);
        float pu0 = (eR ? dp0 : 0.f) - (eL ? dl0 : 0.f);
        float pu1 = (eR ? dp1 : 0.f) - (eL ? dl1 : 0.f);
        float pu2 = (eR ? dp2 : 0.f) - (eL ? dl2 : 0.f);

        float hn[8];
        node_mlp(wN1, bN1, wN2, bN2, h, nu, hn);

        p0 += 0.1f * pu0; p1 += 0.1f * pu1; p2 += 0.1f * pu2;

        if (do_latent && li == 3) {
            latent_mlp(tW1, tB1, tW2, tB2, fW1, fB1, fW2, fB2, hn);
        }

        #pragma unroll
        for (int j = 0; j < 8; ++j) h[j] = hn[j];
    }

    // valid output = lanes 4..59 (halo 4 each side consumed by 4 layers)
    if (lane >= 4 && lane < 60 && n < NTOT) {
        float4* hd = (float4*)(hout + (long)n * 8);
        hd[0] = make_float4(h[0], h[1], h[2], h[3]);
        hd[1] = make_float4(h[4], h[5], h[6], h[7]);
        if (do_pos) ((float4*)pout)[n] = make_float4(p0, p1, p2, 0.f);
    }
}

// ---------------- Kernel 3: decode (h -> pos_out, mask_out) ---------------
// R2-proven version, verbatim.
__global__ __launch_bounds__(256) void k_decode(
    const float* __restrict__ hfin,
    const float* __restrict__ dW1, const float* __restrict__ dB1,
    const float* __restrict__ dW2, const float* __restrict__ dB2,
    const float* __restrict__ mW, const float* __restrict__ mB,
    float* __restrict__ out)
{
    __shared__ alignas(16) float sh[128 * 8];
    __shared__ alignas(16) float st1[128 * 16];
    const int tid = threadIdx.x;
    const long nb = (long)blockIdx.x * 128;

    ((float4*)sh)[tid] = ((const float4*)(hfin + nb * 8))[tid];
    __syncthreads();

    {   // t1 = silu(h @ posdec_W1 + b1): 2 threads per node, 8 cols each
        const int n = tid >> 1;
        const int c0 = (tid & 1) * 8;
        const float4* h4 = (const float4*)(sh + n * 8);
        float4 h0v = h4[0], h1v = h4[1];
        float hr[8] = {h0v.x, h0v.y, h0v.z, h0v.w, h1v.x, h1v.y, h1v.z, h1v.w};
        #pragma unroll
        for (int jj = 0; jj < 8; ++jj) {
            int j = c0 + jj;
            float a = dB1[j];
            #pragma unroll
            for (int r = 0; r < 8; ++r) a += hr[r] * dW1[r * 16 + j];
            st1[n * 16 + j] = silu_f(a);
        }
    }
    __syncthreads();

    if (tid < 222) {
        // ---- pos_out: column-stationary, 2 node-phases ----
        const int half = (tid >= 111) ? 1 : 0;
        const int j = tid - half * 111;
        float w[16];
        #pragma unroll
        for (int r = 0; r < 16; ++r) w[r] = dW2[r * 111 + j];
        const float bj = dB2[j];
        float* op = out + nb * 111 + j;
        #pragma unroll 2
        for (int n = half; n < 128; n += 2) {
            const float4* t4 = (const float4*)(st1 + n * 16);
            float4 a0 = t4[0], a1 = t4[1], a2 = t4[2], a3 = t4[3];
            float acc = bj;
            acc += a0.x * w[0] + a0.y * w[1] + a0.z * w[2] + a0.w * w[3];
            acc += a1.x * w[4] + a1.y * w[5] + a1.z * w[6] + a1.w * w[7];
            acc += a2.x * w[8] + a2.y * w[9] + a2.z * w[10] + a2.w * w[11];
            acc += a3.x * w[12] + a3.y * w[13] + a3.z * w[14] + a3.w * w[15];
            op[n * 111] = acc;
        }
        // ---- mask_out: column-stationary, 6 node-phases ----
        const int g6 = tid / 37;      // 0..5
        const int j2 = tid - g6 * 37;
        float wm[8];
        #pragma unroll
        for (int r = 0; r < 8; ++r) wm[r] = mW[r * 37 + j2];
        const float bm = mB[j2];
        float* omp_ = out + (long)NTOT * 111 + nb * 37 + j2;
        #pragma unroll 1
        for (int n = g6; n < 128; n += 6) {
            const float4* h4 = (const float4*)(sh + n * 8);
            float4 h0v = h4[0], h1v = h4[1];
            float acc = bm;
            acc += h0v.x * wm[0] + h0v.y * wm[1] + h0v.z * wm[2] + h0v.w * wm[3];
            acc += h1v.x * wm[4] + h1v.y * wm[5] + h1v.z * wm[6] + h1v.w * wm[7];
            omp_[n * 37] = acc;
        }
    }
}

extern "C" void kernel_launch(void* const* d_in, const int* in_sizes, int n_in,
                              void* d_out, int out_size, void* d_ws, size_t ws_size,
                              hipStream_t stream) {
    const float* ap     = (const float*)d_in[0];
    const float* amask  = (const float*)d_in[1];
    const float* embW   = (const float*)d_in[2];
    const float* embB   = (const float*)d_in[3];
    const float* peW1   = (const float*)d_in[4];
    const float* peB1   = (const float*)d_in[5];
    const float* peW2   = (const float*)d_in[6];
    const float* peB2   = (const float*)d_in[7];
    const float* ceW1   = (const float*)d_in[8];
    const float* ceB1   = (const float*)d_in[9];
    const float* ceW2   = (const float*)d_in[10];
    const float* ceB2   = (const float*)d_in[11];
    const float* cpW1   = (const float*)d_in[12];
    const float* cpB1   = (const float*)d_in[13];
    const float* cpW2   = (const float*)d_in[14];
    const float* cnW1   = (const float*)d_in[15];
    const float* cnB1   = (const float*)d_in[16];
    const float* cnW2   = (const float*)d_in[17];
    const float* cnB2   = (const float*)d_in[18];
    const float* tW1    = (const float*)d_in[19];
    const float* tB1    = (const float*)d_in[20];
    const float* tW2    = (const float*)d_in[21];
    const float* tB2    = (const float*)d_in[22];
    const float* fW1    = (const float*)d_in[23];
    const float* fB1    = (const float*)d_in[24];
    const float* fW2    = (const float*)d_in[25];
    const float* fB2    = (const float*)d_in[26];
    const float* dW1    = (const float*)d_in[27];
    const float* dB1    = (const float*)d_in[28];
    const float* dW2    = (const float*)d_in[29];
    const float* dB2    = (const float*)d_in[30];
    const float* mW     = (const float*)d_in[31];
    const float* mB     = (const float*)d_in[32];

    float* h0     = (float*)d_ws;                       // 8 MB
    float* pos0   = h0 + (size_t)NTOT * 8;              // 4 MB
    float* hmid   = pos0 + (size_t)NTOT * 4;            // 8 MB
    float* posmid = hmid + (size_t)NTOT * 8;            // 4 MB
    float* hfin   = h0;                                 // h0 dead after kernel A
    float* out    = (float*)d_out;

    k_encode<<<NTOT / 64, 256, 0, stream>>>(ap, amask, embW, embB,
                                            peW1, peB1, peW2, peB2, h0, pos0);
    k_stack4<<<NBLK4, 256, 0, stream>>>(
        h0, pos0, hmid, posmid, 0, 1, 1,
        ceW1, ceB1, ceW2, ceB2, cpW1, cpB1, cpW2,
        cnW1, cnB1, cnW2, cnB2,
        tW1, tB1, tW2, tB2, fW1, fB1, fW2, fB2);
    k_stack4<<<NBLK4, 256, 0, stream>>>(
        hmid, posmid, hfin, posmid, 4, 0, 0,
        ceW1, ceB1, ceW2, ceB2, cpW1, cpB1, cpW2,
        cnW1, cnB1, cnW2, cnB2,
        tW1, tB1, tW2, tB2, fW1, fB1, fW2, fB2);
    k_decode<<<NTOT / 128, 256, 0, stream>>>(hfin, dW1, dB1, dW2, dB2, mW, mB, out);
}

// Round 10
// 434.803 us; speedup vs baseline: 1.5371x; 1.0340x over previous
//
#include <hip/hip_runtime.h>

#define NTOT 262144   // B*L
#define NLAY 8
#define SEGOUT 48     // useful nodes per 64-lane wave (64 nodes incl. 8+8 halo)
#define NSEG ((NTOT + SEGOUT - 1) / SEGOUT)   // 5462

// silu via v_rcp_f32: harness compiles WITHOUT fast-math, so 1.0f/x emits the
// full IEEE divide expansion (~10 VALU ops). v_rcp is 1 op, ~1 ulp — noise vs
// the 2.4e-4 absmax budget. Same for v_sqrt.
__device__ __forceinline__ float silu_f(float x) {
    return x * __builtin_amdgcn_rcpf(1.0f + __expf(-x));
}

// ---------------- Kernel 1: encode  (mask/pos -> h0, pos0) ----------------
// R2-proven version, verbatim — FINAL. 64 nodes/block, 256 threads,
// block-wide float4 staging, quad-split reduce.
// Falsified alternatives: per-wave guarded scalar staging (R3: 367us fused),
// 512-thr block (R6: +6us), direct-global node-per-thread (R7: 938MB fetch,
// 311us — L1 thrash at 148B lane stride).
__global__ __launch_bounds__(256) void k_encode(
    const float* __restrict__ ap, const float* __restrict__ amask,
    const float* __restrict__ embW, const float* __restrict__ embB,
    const float* __restrict__ peW1, const float* __restrict__ peB1,
    const float* __restrict__ peW2, const float* __restrict__ peB2,
    float* __restrict__ h0, float* __restrict__ pos0)
{
    __shared__ alignas(16) float sM[64 * 37];
    __shared__ alignas(16) float sA[64 * 111];
    __shared__ alignas(16) float sW[37 * 8];     // embW staged (296 floats)
    const int tid = threadIdx.x;
    const long nb = (long)blockIdx.x * 64;

    if (tid < 74) ((float4*)sW)[tid] = ((const float4*)embW)[tid];
    const float4* gm = (const float4*)(amask + nb * 37);
    float4* sm4 = (float4*)sM;
    #pragma unroll 1
    for (int i = tid; i < 64 * 37 / 4; i += 256) sm4[i] = gm[i];
    const float4* ga = (const float4*)(ap + nb * 111);
    float4* sa4 = (float4*)sA;
    #pragma unroll 1
    for (int i = tid; i < 64 * 111 / 4; i += 256) sa4[i] = ga[i];
    __syncthreads();

    const int n = tid >> 2;          // node within block
    const int p = tid & 3;           // quad lane
    const int k0 = p * 10;
    const int k1 = (p == 3) ? 37 : k0 + 10;

    const float* mrow = sM + n * 37;
    const float* arow = sA + n * 111;
    float hacc[8] = {0, 0, 0, 0, 0, 0, 0, 0};
    float ps0 = 0.f, ps1 = 0.f, ps2 = 0.f, msum = 0.f;
    #pragma unroll 1
    for (int k = k0; k < k1; ++k) {
        float mv = mrow[k];
        msum += mv;
        const float4* wr = (const float4*)(sW + k * 8);
        float4 w0 = wr[0], w1 = wr[1];
        hacc[0] += mv * w0.x; hacc[1] += mv * w0.y;
        hacc[2] += mv * w0.z; hacc[3] += mv * w0.w;
        hacc[4] += mv * w1.x; hacc[5] += mv * w1.y;
        hacc[6] += mv * w1.z; hacc[7] += mv * w1.w;
        ps0 += mv * arow[k * 3 + 0];
        ps1 += mv * arow[k * 3 + 1];
        ps2 += mv * arow[k * 3 + 2];
    }
    #pragma unroll
    for (int m = 1; m <= 2; m <<= 1) {
        msum += __shfl_xor(msum, m);
        ps0 += __shfl_xor(ps0, m);
        ps1 += __shfl_xor(ps1, m);
        ps2 += __shfl_xor(ps2, m);
        #pragma unroll
        for (int j = 0; j < 8; ++j) hacc[j] += __shfl_xor(hacc[j], m);
    }

    float inv = __builtin_amdgcn_rcpf(msum + 1e-8f);
    float mp0 = ps0 * inv, mp1 = ps1 * inv, mp2 = ps2 * inv;
    float q[8];
    #pragma unroll
    for (int j = 0; j < 8; ++j) {
        float a = peB1[j];
        a += mp0 * peW1[0 * 8 + j];
        a += mp1 * peW1[1 * 8 + j];
        a += mp2 * peW1[2 * 8 + j];
        q[j] = silu_f(a);
    }
    #pragma unroll
    for (int j = 0; j < 8; ++j) {
        float a = peB2[j] + embB[j];
        #pragma unroll
        for (int r = 0; r < 8; ++r) a += q[r] * peW2[r * 8 + j];
        hacc[j] += a;
    }
    const long g = nb + n;
    if (p == 0) ((float4*)(h0 + g * 8))[0] = make_float4(hacc[0], hacc[1], hacc[2], hacc[3]);
    if (p == 1) ((float4*)(h0 + g * 8))[1] = make_float4(hacc[4], hacc[5], hacc[6], hacc[7]);
    if (p == 2) ((float4*)pos0)[g] = make_float4(mp0, mp1, mp2, 0.f);
}

// ---------------- Kernel 2: fused 8-layer SE3 stack + mid latent ----------
// R2-proven version, verbatim — FINAL. Wave-autonomous, 1 node/lane, 8+8
// halo, __shfl neighbor exchange, NO LDS, NO barriers, layer loop unroll 1,
// weights on the global scalar path (s_load/SGPR).
// Falsified alternatives: LDS-staged weights (R5: VGPR 48->224, 10% occ,
// +100us), layer unroll 2 (R8: VALU ops 2x, +29us), 4+4 layer split with
// halved halo (R9: +17us — launch + round-trip beats the 14% compute saving),
// block-level fusion with decode (R4: +40us).
__device__ __forceinline__ void edge_mlp(
    const float* __restrict__ wE1, const float* __restrict__ bE1,
    const float* __restrict__ wE2, const float* __restrict__ bE2,
    const float* __restrict__ wP1, const float* __restrict__ bP1,
    const float* __restrict__ wP2,
    const float* hl, const float* hr, float r0, float r1, float r2,
    float* ea, float& dp0, float& dp1, float& dp2)
{
    float dist = __builtin_amdgcn_sqrtf(r0 * r0 + r1 * r1 + r2 * r2);
    float t1[8];
    #pragma unroll
    for (int j = 0; j < 8; ++j) {
        float a = bE1[j];
        #pragma unroll
        for (int r = 0; r < 8; ++r) a += hl[r] * wE1[r * 8 + j];
        #pragma unroll
        for (int r = 0; r < 8; ++r) a += hr[r] * wE1[64 + r * 8 + j];
        a += dist * wE1[128 + j];
        t1[j] = silu_f(a);
    }
    #pragma unroll
    for (int j = 0; j < 8; ++j) {
        float a = bE2[j];
        #pragma unroll
        for (int r = 0; r < 8; ++r) a += t1[r] * wE2[r * 8 + j];
        ea[j] = a;
    }
    float q[8];
    #pragma unroll
    for (int j = 0; j < 8; ++j) {
        float a = bP1[j];
        #pragma unroll
        for (int r = 0; r < 8; ++r) a += ea[r] * wP1[r * 8 + j];
        q[j] = silu_f(a);
    }
    dp0 = 0.f; dp1 = 0.f; dp2 = 0.f;
    #pragma unroll
    for (int r = 0; r < 8; ++r) {
        dp0 += q[r] * wP2[r * 3 + 0];
        dp1 += q[r] * wP2[r * 3 + 1];
        dp2 += q[r] * wP2[r * 3 + 2];
    }
}

__device__ __forceinline__ void node_mlp(
    const float* __restrict__ wN1, const float* __restrict__ bN1,
    const float* __restrict__ wN2, const float* __restrict__ bN2,
    const float* hl, const float* nu, float* hn)
{
    float u[8];
    #pragma unroll
    for (int j = 0; j < 8; ++j) {
        float a = bN1[j];
        #pragma unroll
        for (int r = 0; r < 8; ++r) a += hl[r] * wN1[r * 8 + j];
        #pragma unroll
        for (int r = 0; r < 8; ++r) a += nu[r] * wN1[64 + r * 8 + j];
        u[j] = silu_f(a);
    }
    #pragma unroll
    for (int j = 0; j < 8; ++j) {
        float a = bN2[j];
        #pragma unroll
        for (int r = 0; r < 8; ++r) a += u[r] * wN2[r * 8 + j];
        hn[j] = a;
    }
}

__device__ __forceinline__ void latent_mlp(
    const float* __restrict__ tW1, const float* __restrict__ tB1,
    const float* __restrict__ tW2, const float* __restrict__ tB2,
    const float* __restrict__ fW1, const float* __restrict__ fB1,
    const float* __restrict__ fW2, const float* __restrict__ fB2,
    float* hn)
{
    float a8[8];
    #pragma unroll
    for (int j = 0; j < 8; ++j) {
        float a = tB1[j];
        #pragma unroll
        for (int r = 0; r < 8; ++r) a += hn[r] * tW1[r * 8 + j];
        a8[j] = silu_f(a);
    }
    float zz[8];
    #pragma unroll
    for (int j = 0; j < 8; ++j) {
        float a = tB2[j];
        #pragma unroll
        for (int r = 0; r < 8; ++r) a += a8[r] * tW2[r * 8 + j];
        zz[j] = a;
    }
    float b8[8];
    #pragma unroll
    for (int j = 0; j < 8; ++j) {
        float a = fB1[j];
        #pragma unroll
        for (int r = 0; r < 8; ++r) a += zz[r] * fW1[r * 8 + j];
        b8[j] = silu_f(a);
    }
    #pragma unroll
    for (int j = 0; j < 8; ++j) {
        float a = fB2[j];
        #pragma unroll
        for (int r = 0; r < 8; ++r) a += b8[r] * fW2[r * 8 + j];
        hn[j] = a;
    }
}

__global__ __launch_bounds__(256) void k_stack(
    const float* __restrict__ h0, const float* __restrict__ pos0,
    float* __restrict__ hfin,
    const float* __restrict__ ceW1, const float* __restrict__ ceB1,
    const float* __restrict__ ceW2, const float* __restrict__ ceB2,
    const float* __restrict__ cpW1, const float* __restrict__ cpB1,
    const float* __restrict__ cpW2,
    const float* __restrict__ cnW1, const float* __restrict__ cnB1,
    const float* __restrict__ cnW2, const float* __restrict__ cnB2,
    const float* __restrict__ tW1, const float* __restrict__ tB1,
    const float* __restrict__ tW2, const float* __restrict__ tB2,
    const float* __restrict__ fW1, const float* __restrict__ fB1,
    const float* __restrict__ fW2, const float* __restrict__ fB2)
{
    const int lane = threadIdx.x & 63;
    const int seg  = blockIdx.x * 4 + (threadIdx.x >> 6);
    const int base = seg * SEGOUT - 8;          // first node of this wave's window
    const int n    = base + lane;               // this lane's node

    float h[8] = {0, 0, 0, 0, 0, 0, 0, 0};
    float p0 = 0.f, p1 = 0.f, p2 = 0.f;
    if (n >= 0 && n < NTOT) {
        const float4* hp = (const float4*)(h0 + (long)n * 8);
        float4 a = hp[0], b = hp[1];
        h[0] = a.x; h[1] = a.y; h[2] = a.z; h[3] = a.w;
        h[4] = b.x; h[5] = b.y; h[6] = b.z; h[7] = b.w;
        float4 p = ((const float4*)pos0)[n];
        p0 = p.x; p1 = p.y; p2 = p.z;
    }

    const bool eR = (n >= 0) && (n + 1 < NTOT);   // edge (n, n+1) exists
    const bool eL = (n >= 1) && (n < NTOT);       // edge (n-1, n) exists

    #pragma unroll 1
    for (int li = 0; li < NLAY; ++li) {
        const float* wE1 = ceW1 + li * 136;
        const float* bE1 = ceB1 + li * 8;
        const float* wE2 = ceW2 + li * 64;
        const float* bE2 = ceB2 + li * 8;
        const float* wP1 = cpW1 + li * 64;
        const float* bP1 = cpB1 + li * 8;
        const float* wP2 = cpW2 + li * 24;
        const float* wN1 = cnW1 + li * 128;
        const float* bN1 = cnB1 + li * 8;
        const float* wN2 = cnW2 + li * 64;
        const float* bN2 = cnB2 + li * 8;

        // right neighbor = next lane's node
        float hr[8], pr0, pr1, pr2;
        #pragma unroll
        for (int j = 0; j < 8; ++j) hr[j] = __shfl_down(h[j], 1);
        pr0 = __shfl_down(p0, 1);
        pr1 = __shfl_down(p1, 1);
        pr2 = __shfl_down(p2, 1);

        float ea[8], dp0, dp1, dp2;
        edge_mlp(wE1, bE1, wE2, bE2, wP1, bP1, wP2,
                 h, hr, pr0 - p0, pr1 - p1, pr2 - p2, ea, dp0, dp1, dp2);

        // left edge of node n = previous lane's edge
        float eaL[8], dl0, dl1, dl2;
        #pragma unroll
        for (int j = 0; j < 8; ++j) eaL[j] = __shfl_up(ea[j], 1);
        dl0 = __shfl_up(dp0, 1);
        dl1 = __shfl_up(dp1, 1);
        dl2 = __shfl_up(dp2, 1);

        float nu[8];
        #pragma unroll
        for (int j = 0; j < 8; ++j)
            nu[j] = (eR ? ea[j] : 0.f) + (eL ? eaL[j] : 0.f);
        float pu0 = (eR ? dp0 : 0.f) - (eL ? dl0 : 0.f);
        float pu1 = (eR ? dp1 : 0.f) - (eL ? dl1 : 0.f);
        float pu2 = (eR ? dp2 : 0.f) - (eL ? dl2 : 0.f);

        float hn[8];
        node_mlp(wN1, bN1, wN2, bN2, h, nu, hn);

        p0 += 0.1f * pu0; p1 += 0.1f * pu1; p2 += 0.1f * pu2;

        if (li == 3) {
            latent_mlp(tW1, tB1, tW2, tB2, fW1, fB1, fW2, fB2, hn);
        }

        #pragma unroll
        for (int j = 0; j < 8; ++j) h[j] = hn[j];
    }

    // valid output = lanes 8..55 (halo 8 each side consumed by 8 layers)
    if (lane >= 8 && lane < 56 && n < NTOT) {
        float4* hd = (float4*)(hfin + (long)n * 8);
        hd[0] = make_float4(h[0], h[1], h[2], h[3]);
        hd[1] = make_float4(h[4], h[5], h[6], h[7]);
    }
}

// ---------------- Kernel 3: decode (h -> pos_out, mask_out) ---------------
// R2-proven version, verbatim — FINAL. Column-stationary, coalesced stores,
// within ~15% of its 155MB write-BW floor.
__global__ __launch_bounds__(256) void k_decode(
    const float* __restrict__ hfin,
    const float* __restrict__ dW1, const float* __restrict__ dB1,
    const float* __restrict__ dW2, const float* __restrict__ dB2,
    const float* __restrict__ mW, const float* __restrict__ mB,
    float* __restrict__ out)
{
    __shared__ alignas(16) float sh[128 * 8];
    __shared__ alignas(16) float st1[128 * 16];
    const int tid = threadIdx.x;
    const long nb = (long)blockIdx.x * 128;

    ((float4*)sh)[tid] = ((const float4*)(hfin + nb * 8))[tid];
    __syncthreads();

    {   // t1 = silu(h @ posdec_W1 + b1): 2 threads per node, 8 cols each
        const int n = tid >> 1;
        const int c0 = (tid & 1) * 8;
        const float4* h4 = (const float4*)(sh + n * 8);
        float4 h0v = h4[0], h1v = h4[1];
        float hr[8] = {h0v.x, h0v.y, h0v.z, h0v.w, h1v.x, h1v.y, h1v.z, h1v.w};
        #pragma unroll
        for (int jj = 0; jj < 8; ++jj) {
            int j = c0 + jj;
            float a = dB1[j];
            #pragma unroll
            for (int r = 0; r < 8; ++r) a += hr[r] * dW1[r * 16 + j];
            st1[n * 16 + j] = silu_f(a);
        }
    }
    __syncthreads();

    if (tid < 222) {
        // ---- pos_out: column-stationary, 2 node-phases ----
        const int half = (tid >= 111) ? 1 : 0;
        const int j = tid - half * 111;
        float w[16];
        #pragma unroll
        for (int r = 0; r < 16; ++r) w[r] = dW2[r * 111 + j];
        const float bj = dB2[j];
        float* op = out + nb * 111 + j;
        #pragma unroll 2
        for (int n = half; n < 128; n += 2) {
            const float4* t4 = (const float4*)(st1 + n * 16);
            float4 a0 = t4[0], a1 = t4[1], a2 = t4[2], a3 = t4[3];
            float acc = bj;
            acc += a0.x * w[0] + a0.y * w[1] + a0.z * w[2] + a0.w * w[3];
            acc += a1.x * w[4] + a1.y * w[5] + a1.z * w[6] + a1.w * w[7];
            acc += a2.x * w[8] + a2.y * w[9] + a2.z * w[10] + a2.w * w[11];
            acc += a3.x * w[12] + a3.y * w[13] + a3.z * w[14] + a3.w * w[15];
            op[n * 111] = acc;
        }
        // ---- mask_out: column-stationary, 6 node-phases ----
        const int g6 = tid / 37;      // 0..5
        const int j2 = tid - g6 * 37;
        float wm[8];
        #pragma unroll
        for (int r = 0; r < 8; ++r) wm[r] = mW[r * 37 + j2];
        const float bm = mB[j2];
        float* omp_ = out + (long)NTOT * 111 + nb * 37 + j2;
        #pragma unroll 1
        for (int n = g6; n < 128; n += 6) {
            const float4* h4 = (const float4*)(sh + n * 8);
            float4 h0v = h4[0], h1v = h4[1];
            float acc = bm;
            acc += h0v.x * wm[0] + h0v.y * wm[1] + h0v.z * wm[2] + h0v.w * wm[3];
            acc += h1v.x * wm[4] + h1v.y * wm[5] + h1v.z * wm[6] + h1v.w * wm[7];
            omp_[n * 37] = acc;
        }
    }
}

extern "C" void kernel_launch(void* const* d_in, const int* in_sizes, int n_in,
                              void* d_out, int out_size, void* d_ws, size_t ws_size,
                              hipStream_t stream) {
    const float* ap     = (const float*)d_in[0];
    const float* amask  = (const float*)d_in[1];
    const float* embW   = (const float*)d_in[2];
    const float* embB   = (const float*)d_in[3];
    const float* peW1   = (const float*)d_in[4];
    const float* peB1   = (const float*)d_in[5];
    const float* peW2   = (const float*)d_in[6];
    const float* peB2   = (const float*)d_in[7];
    const float* ceW1   = (const float*)d_in[8];
    const float* ceB1   = (const float*)d_in[9];
    const float* ceW2   = (const float*)d_in[10];
    const float* ceB2   = (const float*)d_in[11];
    const float* cpW1   = (const float*)d_in[12];
    const float* cpB1   = (const float*)d_in[13];
    const float* cpW2   = (const float*)d_in[14];
    const float* cnW1   = (const float*)d_in[15];
    const float* cnB1   = (const float*)d_in[16];
    const float* cnW2   = (const float*)d_in[17];
    const float* cnB2   = (const float*)d_in[18];
    const float* tW1    = (const float*)d_in[19];
    const float* tB1    = (const float*)d_in[20];
    const float* tW2    = (const float*)d_in[21];
    const float* tB2    = (const float*)d_in[22];
    const float* fW1    = (const float*)d_in[23];
    const float* fB1    = (const float*)d_in[24];
    const float* fW2    = (const float*)d_in[25];
    const float* fB2    = (const float*)d_in[26];
    const float* dW1    = (const float*)d_in[27];
    const float* dB1    = (const float*)d_in[28];
    const float* dW2    = (const float*)d_in[29];
    const float* dB2    = (const float*)d_in[30];
    const float* mW     = (const float*)d_in[31];
    const float* mB     = (const float*)d_in[32];

    float* h0   = (float*)d_ws;
    float* pos0 = h0 + (size_t)NTOT * 8;
    float* hfin = pos0 + (size_t)NTOT * 4;
    float* out  = (float*)d_out;

    k_encode<<<NTOT / 64, 256, 0, stream>>>(ap, amask, embW, embB,
                                            peW1, peB1, peW2, peB2, h0, pos0);
    const int nblk = (NSEG + 3) / 4;   // 4 waves per 256-thread block
    k_stack<<<nblk, 256, 0, stream>>>(
        h0, pos0, hfin,
        ceW1, ceB1, ceW2, ceB2, cpW1, cpB1, cpW2,
        cnW1, cnB1, cnW2, cnB2,
        tW1, tB1, tW2, tB2, fW1, fB1, fW2, fB2);
    k_decode<<<NTOT / 128, 256, 0, stream>>>(hfin, dW1, dB1, dW2, dB2, mW, mB, out);
}